// Round 3
// baseline (75.423 us; speedup 1.0000x reference)
//
#include <hip/hip_runtime.h>

#define BATCH 262144

struct C { float r, i; };

// General rotation: u' = ep*ct*u - st*v ; v' = ep*st*u + ct*v, ep = (cp, sp)
__device__ __forceinline__ void rotp(C& u, C& v, float ct, float st, float cp, float sp) {
    float ar = cp * ct, ai = sp * ct;   // ep*ct
    float br = cp * st, bi = sp * st;   // ep*st
    C nu, nv;
    nu.r = ar * u.r - ai * u.i - st * v.r;
    nu.i = ar * u.i + ai * u.r - st * v.i;
    nv.r = br * u.r - bi * u.i + ct * v.r;
    nv.i = br * u.i + bi * u.r + ct * v.i;
    u = nu; v = nv;
}

// phi == 0: pure real Givens rotation
__device__ __forceinline__ void rotr(C& u, C& v, float ct, float st) {
    C nu, nv;
    nu.r = ct * u.r - st * v.r;
    nu.i = ct * u.i - st * v.i;
    nv.r = st * u.r + ct * v.r;
    nv.i = st * u.i + ct * v.i;
    u = nu; v = nv;
}

__global__ __launch_bounds__(256) void bqnn_kernel(
    const float* __restrict__ x,
    const float* __restrict__ pphi,
    const float* __restrict__ pth,
    const float* __restrict__ ink,
    const float* __restrict__ inb,
    float* __restrict__ out) {
    __shared__ __align__(16) float ls[256 * 15];

    const int t = threadIdx.x;
    const int elem = blockIdx.x * 256 + t;

    // 12 inputs as 3x float4 (48 B/thread; every 128B line fully consumed)
    const float4* x4 = reinterpret_cast<const float4*>(x) + (long long)elem * 3;
    float4 v0 = x4[0], v1 = x4[1], v2 = x4[2];

    const float xs0  = v0.x * ink[0]  + inb[0];
    const float xs1  = v0.y * ink[1]  + inb[1];
    const float xs2  = v0.z * ink[2]  + inb[2];
    const float xs3  = v0.w * ink[3]  + inb[3];
    const float xs4  = v1.x * ink[4]  + inb[4];
    const float xs5  = v1.y * ink[5]  + inb[5];
    const float xs6  = v1.z * ink[6]  + inb[6];
    const float xs7  = v1.w * ink[7]  + inb[7];
    const float xs8  = v2.x * ink[8]  + inb[8];
    const float xs9  = v2.y * ink[9]  + inb[9];
    const float xs10 = v2.z * ink[10] + inb[10];
    const float xs11 = v2.w * ink[11] + inb[11];

    // Only columns 0 and 3 of U are read downstream: two complex 6-vectors
    // in named registers.
    C a0{1.f,0.f}, a1{0.f,0.f}, a2{0.f,0.f}, a3{0.f,0.f}, a4{0.f,0.f}, a5{0.f,0.f};
    C b0{0.f,0.f}, b1{0.f,0.f}, b2{0.f,0.f}, b3{1.f,0.f}, b4{0.f,0.f}, b5{0.f,0.f};

#define ROTR(I, J, TH) do { \
        float st_ = __sinf(TH), ct_ = __cosf(TH); \
        rotr(a##I, a##J, ct_, st_); \
        rotr(b##I, b##J, ct_, st_); \
    } while (0)

#define ROTP(I, J, TH, PH) do { \
        float st_ = __sinf(TH), ct_ = __cosf(TH); \
        float sp_ = __sinf(PH), cp_ = __cosf(PH); \
        rotp(a##I, a##J, ct_, st_, cp_, sp_); \
        rotp(b##I, b##J, ct_, st_, cp_, sp_); \
    } while (0)

    ROTR(0, 1, pth[0]);            // k=0
    ROTR(4, 5, pth[1]);            // k=1
    ROTR(1, 2, pth[2]);            // k=2
    ROTR(3, 4, pth[3]);            // k=3
    ROTP(0, 1, xs3,  xs0);         // k=4
    ROTP(2, 3, xs4,  xs1);         // k=5
    ROTP(4, 5, xs5,  xs2);         // k=6
    ROTP(1, 2, pth[4], pphi[0]);   // k=7
    ROTP(3, 4, pth[5], pphi[1]);   // k=8
    ROTP(0, 1, xs9,  xs6);         // k=9
    ROTP(2, 3, xs10, xs7);         // k=10
    ROTP(4, 5, xs11, xs8);         // k=11
    ROTP(1, 2, pth[6], pphi[2]);   // k=12
    ROTP(3, 4, pth[7], pphi[3]);   // k=13

#undef ROTR
#undef ROTP

#define PAIR(I, J, K) \
    { float re_ = a##I.r * b##J.r - a##I.i * b##J.i + a##J.r * b##I.r - a##J.i * b##I.i; \
      float im_ = a##I.r * b##J.i + a##I.i * b##J.r + a##J.r * b##I.i + a##J.i * b##I.r; \
      m##K = re_ * re_ + im_ * im_; s += m##K; }

    float m0,m1,m2,m3,m4,m5,m6,m7,m8,m9,m10,m11,m12,m13,m14;
    float s = 0.f;
    PAIR(0,1,0)  PAIR(0,2,1)  PAIR(0,3,2)  PAIR(0,4,3)  PAIR(0,5,4)
    PAIR(1,2,5)  PAIR(1,3,6)  PAIR(1,4,7)  PAIR(1,5,8)
    PAIR(2,3,9)  PAIR(2,4,10) PAIR(2,5,11)
    PAIR(3,4,12) PAIR(3,5,13)
    PAIR(4,5,14)
#undef PAIR

    // out_k = sqrt(m_k) * rsq(max(s, eps^2)); approx v_sqrt/v_rsq single-instr
    // ops are exact to ~1-2 ulp -- far inside the 2e-2 threshold.
    float sc = fmaxf(s, 1e-24f);
    float rinv = __builtin_amdgcn_rsqf(sc);

    float* row = ls + t * 15;  // stride 15 (odd) -> conflict-free LDS writes
    row[0]  = __builtin_amdgcn_sqrtf(m0)  * rinv;
    row[1]  = __builtin_amdgcn_sqrtf(m1)  * rinv;
    row[2]  = __builtin_amdgcn_sqrtf(m2)  * rinv;
    row[3]  = __builtin_amdgcn_sqrtf(m3)  * rinv;
    row[4]  = __builtin_amdgcn_sqrtf(m4)  * rinv;
    row[5]  = __builtin_amdgcn_sqrtf(m5)  * rinv;
    row[6]  = __builtin_amdgcn_sqrtf(m6)  * rinv;
    row[7]  = __builtin_amdgcn_sqrtf(m7)  * rinv;
    row[8]  = __builtin_amdgcn_sqrtf(m8)  * rinv;
    row[9]  = __builtin_amdgcn_sqrtf(m9)  * rinv;
    row[10] = __builtin_amdgcn_sqrtf(m10) * rinv;
    row[11] = __builtin_amdgcn_sqrtf(m11) * rinv;
    row[12] = __builtin_amdgcn_sqrtf(m12) * rinv;
    row[13] = __builtin_amdgcn_sqrtf(m13) * rinv;
    row[14] = __builtin_amdgcn_sqrtf(m14) * rinv;

    __syncthreads();

    // Coalesced float4 flush: 960 float4 per block (3840 floats), 4 passes
    // (last one 3/4-predicated). 16 B/lane fully-coalesced stores.
    const float4* ls4 = reinterpret_cast<const float4*>(ls);
    float4* o4 = reinterpret_cast<float4*>(out) + (long long)blockIdx.x * 960;
    #pragma unroll
    for (int i = 0; i < 4; ++i) {
        int idx = i * 256 + t;
        if (idx < 960) o4[idx] = ls4[idx];
    }
}

extern "C" void kernel_launch(void* const* d_in, const int* in_sizes, int n_in,
                              void* d_out, int out_size, void* d_ws, size_t ws_size,
                              hipStream_t stream) {
    const float* x    = (const float*)d_in[0];
    const float* pphi = (const float*)d_in[1];
    const float* pth  = (const float*)d_in[2];
    const float* ink  = (const float*)d_in[3];
    const float* inb  = (const float*)d_in[4];
    float* out = (float*)d_out;

    bqnn_kernel<<<BATCH / 256, 256, 0, stream>>>(x, pphi, pth, ink, inb, out);
}